// Round 2
// baseline (1915.303 us; speedup 1.0000x reference)
//
#include <hip/hip_runtime.h>

// BoostedNeuralLDPCDecoder — MI355X HIP implementation (round 6)
//
// Round 5 (cooperative launch) aborted: hipLaunchCooperativeKernel is not
// graph-capture-safe in this harness. Same fusion theory (11 dispatches are
// serialization-bound; ideal phase sum ~50 us vs 189.6 us measured), new
// mechanism: persistent kernel + hand-rolled device-scope grid barrier.
//
//  * Plain <<<>>> launch, grid = 1024 = 4 blocks/CU x 256 CUs. Residency is
//    guaranteed by __launch_bounds__(256,4) (VGPR<=128) + 5.9 KB LDS/block,
//    so the spin barrier cannot deadlock.
//  * Barrier: per-phase counter; release-scope atomicAdd + acquire-scope spin
//    (agent scope) + __threadfence() — the same lowering ROCm grid.sync uses,
//    valid across non-coherent per-XCD L2s. 9 distinct counters, zeroed by a
//    64 B hipMemsetAsync before the kernel (capture-safe, re-poison-proof).
//  * Inner arithmetic verbatim from the verified round-4 kernels (absmax 0.0).
//  * CN phase: flat grid-stride; 64 | 384 keeps each wave inside one (cn,b)
//    -> readfirstlane scalarization of edge tables preserved.
//  * VN phase: verbatim 17x64 tile, tile id nchunk-fastest for L2 write-merge.
//  * init (dummy row + voff table) on blocks 0/1, overlapped with cn0.
//
// Layouts (lane = z => coalesced, incl. shifted circulant access):
//   tot  [N][B][Z] float      (6.68 MB)
//   c2v  [E+1][B][Z] int8     (9.07 MB) value = 2*message in [-15,15]; row E = 0
//   vn_deg[N], voff[N][24] (byte offsets e*B*Z; dummy = E*B*Z)

#define ITERS 5
#define Nn 68
#define Mm 46
#define Zz 384
#define Ee 368
#define Bb 64
#define Kk 8          // edges per CN (E/M)
#define PADD 24       // padded max VN degree
#define BIGF 1e9f

#define ROWB (Bb*Zz)                     // 24,576 bytes per c2v edge-row
#define TOT_ELEMS (Nn*Bb*Zz)             // 1,671,168 floats
#define C2V_BYTES ((Ee+1)*ROWB)          // 9,068,544 bytes (incl. zero row)
#define TOT_OFF   0
#define C2V_OFF   (TOT_ELEMS*4)          // 6,684,672
#define DEG_OFF   (C2V_OFF + C2V_BYTES)  // 15,753,216
#define BAR_OFF   (DEG_OFF + 288)        // barrier counters in vn_deg padding
#define VOFF_OFF  (DEG_OFF + 384)        // 15,753,600
// total ws need: VOFF_OFF + Nn*PADD*4 = 15,760,128 bytes (~15.8 MB, unchanged)

#define BLK 256
#define NBLOCKS 1024                     // 4 blocks/CU x 256 CUs — all resident
#define CN_TOTAL (Mm*Bb*Zz)              // 1,130,496 check-lane units
#define VN_TILES (Bb*6*4)                // 1536 tiles (b, z/64, n/17)
#define OUT_ITER ((size_t)Bb*Zz*Nn)

// ---- device-scope grid barrier (one counter per use; pre-zeroed) ----
__device__ __forceinline__ void gbar(unsigned* __restrict__ bar, int idx)
{
    __syncthreads();                     // all waves' stores vmcnt-drained
    if (threadIdx.x == 0) {
        __threadfence();                 // release: write back this XCD's caches
        __hip_atomic_fetch_add(bar + idx, 1u, __ATOMIC_RELEASE,
                               __HIP_MEMORY_SCOPE_AGENT);
        while (__hip_atomic_load(bar + idx, __ATOMIC_ACQUIRE,
                                 __HIP_MEMORY_SCOPE_AGENT) < (unsigned)NBLOCKS)
            __builtin_amdgcn_s_sleep(1);
        __threadfence();                 // acquire: invalidate before re-reads
    }
    __syncthreads();
}

// ---- min-sum tail: verbatim from round 4 ----
__device__ __forceinline__ void minsum_store(
    const float v[Kk], const int off[Kk], float m1, unsigned sflip,
    float w, signed char* __restrict__ c2v)
{
    // min2 over entries whose |v| != min1 (reference tie semantics, BIG if none)
    float m2 = BIGF;
    #pragma unroll
    for (int k = 0; k < Kk; k++) {
        float mag = fabsf(v[k]);
        if (mag != m1) m2 = fminf(m2, mag);
    }
    #pragma unroll
    for (int k = 0; k < Kk; k++) {
        float mag  = fabsf(v[k]);
        float emin = (mag == m1) ? m2 : m1;
        unsigned neg = sflip ^ ((v[k] < 0.0f) ? 1u : 0u);  // csign * own_sign
        float ext = neg ? -emin : emin;
        // _qms5(w * ext): forward == clip(rintf(2*x)/2, +-7.5); store 2*q as int8
        float r = rintf(w * ext * 2.0f);
        r = fminf(15.0f, fmaxf(-15.0f, r));
        c2v[off[k]] = (signed char)(int)r;
    }
}

// ---- CN phase: flat grid-stride; FIRST reads xa directly (c2v == 0) ----
template<bool FIRST>
__device__ __forceinline__ void cn_pass(
    const float* __restrict__ src,       // FIRST ? xa [B][N][Z] : tot [N][B][Z]
    signed char* __restrict__ c2v,
    const int* __restrict__ edge_vn, const int* __restrict__ edge_shift,
    float w)
{
    for (int u = blockIdx.x * BLK + threadIdx.x; u < CN_TOTAL;
         u += NBLOCKS * BLK) {
        // whole wave lies in one (cn,b): base 64-aligned and 64 | 384
        const int pair = __builtin_amdgcn_readfirstlane(u) / Zz;
        const int zc   = u - pair * Zz;          // per-lane lifted row
        const int cn   = pair % Mm;
        const int b    = pair / Mm;

        float v[Kk];
        int   off[Kk];
        float m1 = BIGF;
        unsigned sflip = 0u;

        #pragma unroll
        for (int k = 0; k < Kk; k++) {
            int e  = cn + k * Mm;        // edges of this check (edge_cn = e % M)
            int sh = edge_shift[e];      // wave-uniform -> scalar load
            int n  = edge_vn[e];         // wave-uniform
            int z  = zc - sh;
            z += (z >> 31) & Zz;         // mod Z
            int o = e * ROWB + b * Zz + z;
            off[k] = o;
            float x;
            if (FIRST) {
                x = src[(b * Nn + n) * Zz + z];   // belief; no c2v subtract at it 0
            } else {
                float t = src[(n * Bb + b) * Zz + z];   // VN belief
                x = t - 0.5f * (float)c2v[o];           // extrinsic (one rounding)
            }
            x = fminf(20.0f, fmaxf(-20.0f, x));  // allowed_llr_range
            v[k] = x;
            if (x < 0.0f) sflip ^= 1u;
            m1 = fminf(m1, fabsf(x));
        }
        minsum_store(v, off, m1, sflip, w, c2v);
    }
}

// ---- VN phase: verbatim tile logic, tile id remapped nchunk-fastest ----
__device__ __forceinline__ void vn_pass(
    const float* __restrict__ xa, const signed char* __restrict__ c2v,
    float* __restrict__ tot, float* __restrict__ out_it,
    const int* __restrict__ vn_deg, const int* __restrict__ voff,
    int write_tot, float (*tile)[65])
{
    const int wave = threadIdx.x >> 6;
    const int lane = threadIdx.x & 63;
    for (int t = blockIdx.x; t < VN_TILES; t += NBLOCKS) {
        const int nc   = t & 3;          // n-chunk FASTEST: adjacent blocks share
        const int rest = t >> 2;         //   out cache lines -> L2 write-merge
        const int zq   = rest % 6;
        const int b    = rest / 6;
        const int z0 = zq * 64, n0 = nc * 17;
        const int z  = z0 + lane;
        const int bz = b * Zz + z;       // offset within a c2v edge-row

        for (int i = wave; i < 17; i += 4) {
            int n = __builtin_amdgcn_readfirstlane(n0 + i);  // scalar table loads
            int d = vn_deg[n];                               // wave-uniform
            const int* vo = voff + n * PADD;
            int acc = 0;                 // sum of int8 messages (2x value): exact
            #pragma unroll
            for (int j = 0; j < 8; j++) acc += (int)c2v[vo[j] + bz];
            if (d > 8) {
                #pragma unroll
                for (int j = 8; j < 16; j++) acc += (int)c2v[vo[j] + bz];
            }
            if (d > 16) {
                #pragma unroll
                for (int j = 16; j < PADD; j++) acc += (int)c2v[vo[j] + bz];
            }
            float s = xa[(size_t)(b * Nn + n) * Zz + z] + 0.5f * (float)acc;
            if (write_tot) tot[(n * Bb + b) * Zz + z] = s;
            tile[i][lane] = s;
        }
        __syncthreads();

        // out[it][b][z][n]: 64 z-rows x 17 contiguous floats (68 B segments)
        float* dst = out_it + ((size_t)b * Zz + z0) * Nn + n0;
        for (int idx = threadIdx.x; idx < 17 * 64; idx += BLK) {
            int zz = idx / 17;
            int nn = idx - zz * 17;
            dst[(size_t)zz * Nn + nn] = tile[nn][zz];
        }
        __syncthreads();                 // tile reused by next grid-stride tile
    }
}

__global__ __launch_bounds__(BLK, 4) void fused_kernel(
    const float* __restrict__ xa, const float* __restrict__ cn_weight,
    const int* __restrict__ edge_vn, const int* __restrict__ edge_shift,
    float* __restrict__ tot, signed char* __restrict__ c2v,
    int* __restrict__ vn_deg, int* __restrict__ voff,
    unsigned* __restrict__ bar, float* __restrict__ out)
{
    __shared__ float tile[17][65];       // [n_local][z_local+1 pad]
    __shared__ int   sev[Ee];

    // ---- init, overlapped with cn0 (consumers read only after barrier 0) ----
    if (blockIdx.x == 0) {
        // dummy row = zeros; 24,576 B = 1536 int4
        int4* p = (int4*)(c2v + (size_t)Ee * ROWB);
        for (int i = threadIdx.x; i < ROWB / 16; i += BLK)
            p[i] = make_int4(0, 0, 0, 0);
    } else if (blockIdx.x == 1) {
        // padded per-VN offset table; LDS staging kills the load chain
        for (int t = threadIdx.x; t < Ee; t += BLK) sev[t] = edge_vn[t];
        __syncthreads();
        int n = threadIdx.x;
        if (n < Nn) {
            int d = 0;
            for (int e = 0; e < Ee; e++)
                if (sev[e] == n && d < PADD) voff[n * PADD + (d++)] = e * ROWB;
            vn_deg[n] = d;
            for (int j = d; j < PADD; j++) voff[n * PADD + j] = Ee * ROWB;
        }
    }

    for (int it = 0; it < ITERS; ++it) {
        const float w = cn_weight[it];
        if (it == 0) cn_pass<true >(xa,  c2v, edge_vn, edge_shift, w);
        else         cn_pass<false>(tot, c2v, edge_vn, edge_shift, w);
        gbar(bar, 2 * it);                           // c2v (+init tables) ready
        vn_pass(xa, c2v, tot, out + (size_t)it * OUT_ITER,
                vn_deg, voff, (it != ITERS - 1) ? 1 : 0, tile);
        if (it != ITERS - 1) gbar(bar, 2 * it + 1);  // tot ready
    }
}

extern "C" void kernel_launch(void* const* d_in, const int* in_sizes, int n_in,
                              void* d_out, int out_size, void* d_ws, size_t ws_size,
                              hipStream_t stream) {
    const float* xa        = (const float*)d_in[0];  // [B][N][Z]
    const float* cn_weight = (const float*)d_in[1];  // [ITERS]
    const int*   edge_vn   = (const int*)d_in[2];    // [E]
    // d_in[3] = edge_cn: structurally e % M, not needed
    const int*   edge_shift= (const int*)d_in[4];    // [E]
    float* out = (float*)d_out;                      // [ITERS][B][Z][N]

    char* ws = (char*)d_ws;
    float*       tot    = (float*)(ws + TOT_OFF);
    signed char* c2v    = (signed char*)(ws + C2V_OFF);
    int*         vn_deg = (int*)(ws + DEG_OFF);
    unsigned*    bar    = (unsigned*)(ws + BAR_OFF);
    int*         voff   = (int*)(ws + VOFF_OFF);

    // zero the 9 barrier counters (64 B) — capture-safe, re-poison-proof
    hipMemsetAsync(ws + BAR_OFF, 0, 64, stream);

    fused_kernel<<<dim3(NBLOCKS), dim3(BLK), 0, stream>>>(
        xa, cn_weight, edge_vn, edge_shift, tot, c2v, vn_deg, voff, bar, out);
}

// Round 3
// 1516.672 us; speedup vs baseline: 1.2628x; 1.2628x over previous
//
#include <hip/hip_runtime.h>

// BoostedNeuralLDPCDecoder — MI355X HIP implementation (round 7)
//
// Round 6 (fused + spin barrier) passed but ran 1915 us: the barrier polled
// with ACQUIRE agent-scope loads, each lowering to global_load + buffer_inv —
// a cache-wide invalidate every ~64 cycles per spinning block. The invalidate
// storm made polls slow AND evicted the working set of still-computing blocks
// (FETCH_SIZE 154 MB vs ~40 MB logical). Fix, keeping the fusion:
//  * poll with RELAXED agent atomic loads (global_load sc1, no invalidate),
//    s_sleep(8) between polls, ACQUIRE safety-valve every 256 polls;
//  * ONE acquire fence per block per barrier after the spin exits;
//  * grid 1536 = 6 blocks/CU (launch_bounds(256,6), VGPR 28, LDS 36.9 KB/CU):
//    VN phase = exactly 1 tile/block, CN wall 5 -> 3 stride iterations, and
//    2 blocks/CU residency slack protects the spin against capacity surprises.
// Inner arithmetic is verbatim round-4 (absmax 0.0 must be preserved).
//
// Layouts (lane = z => coalesced, incl. shifted circulant access):
//   tot  [N][B][Z] float      (6.68 MB)
//   c2v  [E+1][B][Z] int8     (9.07 MB) value = 2*message in [-15,15]; row E = 0
//   vn_deg[N], voff[N][24] (byte offsets e*B*Z; dummy = E*B*Z)

#define ITERS 5
#define Nn 68
#define Mm 46
#define Zz 384
#define Ee 368
#define Bb 64
#define Kk 8          // edges per CN (E/M)
#define PADD 24       // padded max VN degree
#define BIGF 1e9f

#define ROWB (Bb*Zz)                     // 24,576 bytes per c2v edge-row
#define TOT_ELEMS (Nn*Bb*Zz)             // 1,671,168 floats
#define C2V_BYTES ((Ee+1)*ROWB)          // 9,068,544 bytes (incl. zero row)
#define TOT_OFF   0
#define C2V_OFF   (TOT_ELEMS*4)          // 6,684,672
#define DEG_OFF   (C2V_OFF + C2V_BYTES)  // 15,753,216
#define BAR_OFF   (DEG_OFF + 288)        // 9 barrier counters in vn_deg padding
#define VOFF_OFF  (DEG_OFF + 384)        // 15,753,600
// total ws need: VOFF_OFF + Nn*PADD*4 = 15,760,128 bytes (~15.8 MB, unchanged)

#define BLK 256
#define NBLOCKS 1536                     // 6 blocks/CU x 256 CUs — all resident
#define CN_TOTAL (Mm*Bb*Zz)              // 1,130,496 check-lane units
#define VN_TILES (Bb*6*4)                // 1536 tiles (b, z/64, n/17) = NBLOCKS
#define OUT_ITER ((size_t)Bb*Zz*Nn)

// ---- device-scope grid barrier (one counter per use; pre-zeroed) ----
// Arrival: release fetch_add (publishes this block's stores via L2 writeback).
// Wait: RELAXED agent loads (coherence-point read, NO cache invalidate) with
// s_sleep backoff; ACQUIRE safety-valve every 256 polls guarantees progress
// even if a relaxed load were ever cache-served. One acquire fence at exit.
__device__ __forceinline__ void gbar(unsigned* __restrict__ bar, int idx)
{
    __syncthreads();                     // all waves' stores vmcnt-drained
    if (threadIdx.x == 0) {
        __hip_atomic_fetch_add(bar + idx, 1u, __ATOMIC_RELEASE,
                               __HIP_MEMORY_SCOPE_AGENT);
        unsigned c;
        int spins = 0;
        for (;;) {
            c = __hip_atomic_load(bar + idx, __ATOMIC_RELAXED,
                                  __HIP_MEMORY_SCOPE_AGENT);
            if (c >= (unsigned)NBLOCKS) break;
            __builtin_amdgcn_s_sleep(8);
            if ((++spins & 255) == 0) {  // safety valve (never hot)
                c = __hip_atomic_load(bar + idx, __ATOMIC_ACQUIRE,
                                      __HIP_MEMORY_SCOPE_AGENT);
                if (c >= (unsigned)NBLOCKS) break;
            }
        }
        __builtin_amdgcn_fence(__ATOMIC_ACQUIRE, "agent"); // one inv per block
    }
    __syncthreads();
}

// ---- min-sum tail: verbatim from round 4 ----
__device__ __forceinline__ void minsum_store(
    const float v[Kk], const int off[Kk], float m1, unsigned sflip,
    float w, signed char* __restrict__ c2v)
{
    // min2 over entries whose |v| != min1 (reference tie semantics, BIG if none)
    float m2 = BIGF;
    #pragma unroll
    for (int k = 0; k < Kk; k++) {
        float mag = fabsf(v[k]);
        if (mag != m1) m2 = fminf(m2, mag);
    }
    #pragma unroll
    for (int k = 0; k < Kk; k++) {
        float mag  = fabsf(v[k]);
        float emin = (mag == m1) ? m2 : m1;
        unsigned neg = sflip ^ ((v[k] < 0.0f) ? 1u : 0u);  // csign * own_sign
        float ext = neg ? -emin : emin;
        // _qms5(w * ext): forward == clip(rintf(2*x)/2, +-7.5); store 2*q as int8
        float r = rintf(w * ext * 2.0f);
        r = fminf(15.0f, fmaxf(-15.0f, r));
        c2v[off[k]] = (signed char)(int)r;
    }
}

// ---- CN phase: flat grid-stride; FIRST reads xa directly (c2v == 0) ----
template<bool FIRST>
__device__ __forceinline__ void cn_pass(
    const float* __restrict__ src,       // FIRST ? xa [B][N][Z] : tot [N][B][Z]
    signed char* __restrict__ c2v,
    const int* __restrict__ edge_vn, const int* __restrict__ edge_shift,
    float w)
{
    for (int u = blockIdx.x * BLK + threadIdx.x; u < CN_TOTAL;
         u += NBLOCKS * BLK) {
        // whole wave lies in one (cn,b): base 64-aligned and 64 | 384
        const int pair = __builtin_amdgcn_readfirstlane(u) / Zz;
        const int zc   = u - pair * Zz;          // per-lane lifted row
        const int cn   = pair % Mm;
        const int b    = pair / Mm;

        float v[Kk];
        int   off[Kk];
        float m1 = BIGF;
        unsigned sflip = 0u;

        #pragma unroll
        for (int k = 0; k < Kk; k++) {
            int e  = cn + k * Mm;        // edges of this check (edge_cn = e % M)
            int sh = edge_shift[e];      // wave-uniform -> scalar load
            int n  = edge_vn[e];         // wave-uniform
            int z  = zc - sh;
            z += (z >> 31) & Zz;         // mod Z
            int o = e * ROWB + b * Zz + z;
            off[k] = o;
            float x;
            if (FIRST) {
                x = src[(b * Nn + n) * Zz + z];   // belief; no c2v subtract at it 0
            } else {
                float t = src[(n * Bb + b) * Zz + z];   // VN belief
                x = t - 0.5f * (float)c2v[o];           // extrinsic (one rounding)
            }
            x = fminf(20.0f, fmaxf(-20.0f, x));  // allowed_llr_range
            v[k] = x;
            if (x < 0.0f) sflip ^= 1u;
            m1 = fminf(m1, fabsf(x));
        }
        minsum_store(v, off, m1, sflip, w, c2v);
    }
}

// ---- VN phase: verbatim tile logic; exactly one tile per block ----
__device__ __forceinline__ void vn_pass(
    const float* __restrict__ xa, const signed char* __restrict__ c2v,
    float* __restrict__ tot, float* __restrict__ out_it,
    const int* __restrict__ vn_deg, const int* __restrict__ voff,
    int write_tot, float (*tile)[65])
{
    const int wave = threadIdx.x >> 6;
    const int lane = threadIdx.x & 63;
    for (int t = blockIdx.x; t < VN_TILES; t += NBLOCKS) {
        const int nc   = t & 3;          // n-chunk FASTEST: adjacent blocks share
        const int rest = t >> 2;         //   out cache lines -> L2 write-merge
        const int zq   = rest % 6;
        const int b    = rest / 6;
        const int z0 = zq * 64, n0 = nc * 17;
        const int z  = z0 + lane;
        const int bz = b * Zz + z;       // offset within a c2v edge-row

        for (int i = wave; i < 17; i += 4) {
            int n = __builtin_amdgcn_readfirstlane(n0 + i);  // scalar table loads
            int d = vn_deg[n];                               // wave-uniform
            const int* vo = voff + n * PADD;
            int acc = 0;                 // sum of int8 messages (2x value): exact
            #pragma unroll
            for (int j = 0; j < 8; j++) acc += (int)c2v[vo[j] + bz];
            if (d > 8) {
                #pragma unroll
                for (int j = 8; j < 16; j++) acc += (int)c2v[vo[j] + bz];
            }
            if (d > 16) {
                #pragma unroll
                for (int j = 16; j < PADD; j++) acc += (int)c2v[vo[j] + bz];
            }
            float s = xa[(size_t)(b * Nn + n) * Zz + z] + 0.5f * (float)acc;
            if (write_tot) tot[(n * Bb + b) * Zz + z] = s;
            tile[i][lane] = s;
        }
        __syncthreads();

        // out[it][b][z][n]: 64 z-rows x 17 contiguous floats (68 B segments)
        float* dst = out_it + ((size_t)b * Zz + z0) * Nn + n0;
        for (int idx = threadIdx.x; idx < 17 * 64; idx += BLK) {
            int zz = idx / 17;
            int nn = idx - zz * 17;
            dst[(size_t)zz * Nn + nn] = tile[nn][zz];
        }
        __syncthreads();                 // tile reused if block ever loops
    }
}

__global__ __launch_bounds__(BLK, 6) void fused_kernel(
    const float* __restrict__ xa, const float* __restrict__ cn_weight,
    const int* __restrict__ edge_vn, const int* __restrict__ edge_shift,
    float* __restrict__ tot, signed char* __restrict__ c2v,
    int* __restrict__ vn_deg, int* __restrict__ voff,
    unsigned* __restrict__ bar, float* __restrict__ out)
{
    __shared__ float tile[17][65];       // [n_local][z_local+1 pad]
    __shared__ int   sev[Ee];

    // ---- init, overlapped with cn0 (consumers read only after barrier 0) ----
    if (blockIdx.x == 0) {
        // dummy row = zeros; 24,576 B = 1536 int4
        int4* p = (int4*)(c2v + (size_t)Ee * ROWB);
        for (int i = threadIdx.x; i < ROWB / 16; i += BLK)
            p[i] = make_int4(0, 0, 0, 0);
    } else if (blockIdx.x == 1) {
        // padded per-VN offset table; LDS staging kills the load chain
        for (int t = threadIdx.x; t < Ee; t += BLK) sev[t] = edge_vn[t];
        __syncthreads();
        int n = threadIdx.x;
        if (n < Nn) {
            int d = 0;
            for (int e = 0; e < Ee; e++)
                if (sev[e] == n && d < PADD) voff[n * PADD + (d++)] = e * ROWB;
            vn_deg[n] = d;
            for (int j = d; j < PADD; j++) voff[n * PADD + j] = Ee * ROWB;
        }
    }

    for (int it = 0; it < ITERS; ++it) {
        const float w = cn_weight[it];
        if (it == 0) cn_pass<true >(xa,  c2v, edge_vn, edge_shift, w);
        else         cn_pass<false>(tot, c2v, edge_vn, edge_shift, w);
        gbar(bar, 2 * it);                           // c2v (+init tables) ready
        vn_pass(xa, c2v, tot, out + (size_t)it * OUT_ITER,
                vn_deg, voff, (it != ITERS - 1) ? 1 : 0, tile);
        if (it != ITERS - 1) gbar(bar, 2 * it + 1);  // tot ready
    }
}

extern "C" void kernel_launch(void* const* d_in, const int* in_sizes, int n_in,
                              void* d_out, int out_size, void* d_ws, size_t ws_size,
                              hipStream_t stream) {
    const float* xa        = (const float*)d_in[0];  // [B][N][Z]
    const float* cn_weight = (const float*)d_in[1];  // [ITERS]
    const int*   edge_vn   = (const int*)d_in[2];    // [E]
    // d_in[3] = edge_cn: structurally e % M, not needed
    const int*   edge_shift= (const int*)d_in[4];    // [E]
    float* out = (float*)d_out;                      // [ITERS][B][Z][N]

    char* ws = (char*)d_ws;
    float*       tot    = (float*)(ws + TOT_OFF);
    signed char* c2v    = (signed char*)(ws + C2V_OFF);
    int*         vn_deg = (int*)(ws + DEG_OFF);
    unsigned*    bar    = (unsigned*)(ws + BAR_OFF);
    int*         voff   = (int*)(ws + VOFF_OFF);

    // zero the 9 barrier counters (64 B) — capture-safe, re-poison-proof
    hipMemsetAsync(ws + BAR_OFF, 0, 64, stream);

    fused_kernel<<<dim3(NBLOCKS), dim3(BLK), 0, stream>>>(
        xa, cn_weight, edge_vn, edge_shift, tot, c2v, vn_deg, voff, bar, out);
}

// Round 4
// 767.108 us; speedup vs baseline: 2.4968x; 1.9771x over previous
//
#include <hip/hip_runtime.h>

// BoostedNeuralLDPCDecoder — MI355X HIP implementation (round 8)
//
// Round 7 post-mortem: RELAXED agent-scope polls are served from the polling
// XCD's own (non-coherent, never-invalidated) L1/L2 -> the spin loop never
// sees the counter advance; progress only happened at the ACQUIRE safety
// valve every ~256 sleeps (~60-150 us) -> 9 barriers quantized to ~1.4 ms of
// dead time (VALUBusy 3.5%). Fixes:
//  1) Poll with SYSTEM-scope relaxed atomic loads (global_load sc0 sc1 —
//     bypasses L1 AND the non-coherent L2, reads the memory-side LLC which is
//     always fresh; no invalidate side effects). ACQUIRE valve every 16 polls
//     as a lowering backstop; one acquire fence at exit (needed anyway for
//     cached cross-XCD data reads).
//  2) Per-BATCH barriers instead of one global barrier: the problem is fully
//     independent per b (tot/c2v/out slices disjoint). 64 groups x 24 blocks,
//     per-group counters on separate 64 B lines: 24 same-line arrivals
//     instead of 1536, wait = group skew not global straggler, and groups
//     desynchronize (CN of one batch overlaps VN of another).
//  VN gather tables (deg/voff) now built per block in LDS (order-independent
//  integer sums -> bit-exact), removing the cross-group init dependency; each
//  group zeroes its own 384 B dummy-row slice before barrier 0.
// Inner arithmetic verbatim round-4 (absmax 0.0 must be preserved).
//
// Layouts (lane = z => coalesced, incl. shifted circulant access):
//   tot  [N][B][Z] float      (6.68 MB)
//   c2v  [E+1][B][Z] int8     (9.07 MB) value = 2*message in [-15,15]; row E = 0
//   bar  [64 groups][16 uints] (4 KB; one 64 B line per group, 9 used)

#define ITERS 5
#define Nn 68
#define Mm 46
#define Zz 384
#define Ee 368
#define Bb 64
#define Kk 8          // edges per CN (E/M)
#define PADD 24       // padded max VN degree
#define BIGF 1e9f

#define ROWB (Bb*Zz)                     // 24,576 bytes per c2v edge-row
#define TOT_ELEMS (Nn*Bb*Zz)             // 1,671,168 floats
#define C2V_BYTES ((Ee+1)*ROWB)          // 9,068,544 bytes (incl. zero row)
#define TOT_OFF   0
#define C2V_OFF   (TOT_ELEMS*4)          // 6,684,672
#define BAR_OFF   (C2V_OFF + C2V_BYTES)  // 15,753,216; 4 KB of counters
// total ws need: BAR_OFF + 4096 = 15,757,312 bytes (< round-4's 15,760,128)

#define BLK 256
#define GBLK 24                          // blocks per group (= per batch b)
#define GROUPS 64                        // one group per b; 24*64 = 1536 blocks
#define CNU (Mm*Zz)                      // 17,664 check-lane units per group
#define OUT_ITER ((size_t)Bb*Zz*Nn)

// ---- per-group barrier ----
// Arrival: RELEASE agent fetch_add (wbl2 publishes this block's stores).
// Wait: SYSTEM-scope relaxed atomic loads — read the memory-side LLC (always
// coherent), no cache-maintenance side effects. ACQUIRE valve every 16 polls
// guarantees progress even if the relaxed lowering were cache-served.
// Exit: one acquire fence (inv) so cached loads see cross-XCD data.
__device__ __forceinline__ void gbar(unsigned* __restrict__ ctr)
{
    __syncthreads();                     // all waves' loads/stores vmcnt-drained
    if (threadIdx.x == 0) {
        __hip_atomic_fetch_add(ctr, 1u, __ATOMIC_RELEASE,
                               __HIP_MEMORY_SCOPE_AGENT);
        int spins = 0;
        for (;;) {
            unsigned c = __hip_atomic_load(ctr, __ATOMIC_RELAXED,
                                           __HIP_MEMORY_SCOPE_SYSTEM);
            if (c >= (unsigned)GBLK) break;
            __builtin_amdgcn_s_sleep(8);
            if ((++spins & 15) == 0) {   // backstop: fresh-by-construction
                c = __hip_atomic_load(ctr, __ATOMIC_ACQUIRE,
                                      __HIP_MEMORY_SCOPE_AGENT);
                if (c >= (unsigned)GBLK) break;
            }
        }
        __builtin_amdgcn_fence(__ATOMIC_ACQUIRE, "agent");  // one inv per block
    }
    __syncthreads();
}

// ---- min-sum tail: verbatim from round 4 ----
__device__ __forceinline__ void minsum_store(
    const float v[Kk], const int off[Kk], float m1, unsigned sflip,
    float w, signed char* __restrict__ c2v)
{
    // min2 over entries whose |v| != min1 (reference tie semantics, BIG if none)
    float m2 = BIGF;
    #pragma unroll
    for (int k = 0; k < Kk; k++) {
        float mag = fabsf(v[k]);
        if (mag != m1) m2 = fminf(m2, mag);
    }
    #pragma unroll
    for (int k = 0; k < Kk; k++) {
        float mag  = fabsf(v[k]);
        float emin = (mag == m1) ? m2 : m1;
        unsigned neg = sflip ^ ((v[k] < 0.0f) ? 1u : 0u);  // csign * own_sign
        float ext = neg ? -emin : emin;
        // _qms5(w * ext): forward == clip(rintf(2*x)/2, +-7.5); store 2*q as int8
        float r = rintf(w * ext * 2.0f);
        r = fminf(15.0f, fmaxf(-15.0f, r));
        c2v[off[k]] = (signed char)(int)r;
    }
}

// ---- CN phase for one group (batch b = g); FIRST reads xa (c2v == 0) ----
template<bool FIRST>
__device__ __forceinline__ void cn_pass(
    const float* __restrict__ src,       // FIRST ? xa [B][N][Z] : tot [N][B][Z]
    signed char* __restrict__ c2v,
    const int* __restrict__ edge_vn, const int* __restrict__ edge_shift,
    float w, int g, int r)
{
    for (int u = r * BLK + threadIdx.x; u < CNU; u += GBLK * BLK) {
        // whole wave lies in one cn: base 64-aligned and 64 | 384
        const int cn = __builtin_amdgcn_readfirstlane(u) / Zz;
        const int zc = u - cn * Zz;      // per-lane lifted row

        float v[Kk];
        int   off[Kk];
        float m1 = BIGF;
        unsigned sflip = 0u;

        #pragma unroll
        for (int k = 0; k < Kk; k++) {
            int e  = cn + k * Mm;        // edges of this check (edge_cn = e % M)
            int sh = edge_shift[e];      // wave-uniform -> scalar load
            int n  = edge_vn[e];         // wave-uniform
            int z  = zc - sh;
            z += (z >> 31) & Zz;         // mod Z
            int o = e * ROWB + g * Zz + z;
            off[k] = o;
            float x;
            if (FIRST) {
                x = src[(g * Nn + n) * Zz + z];   // belief; no c2v subtract at it 0
            } else {
                float t = src[(n * Bb + g) * Zz + z];   // VN belief
                x = t - 0.5f * (float)c2v[o];           // extrinsic (one rounding)
            }
            x = fminf(20.0f, fmaxf(-20.0f, x));  // allowed_llr_range
            v[k] = x;
            if (x < 0.0f) sflip ^= 1u;
            m1 = fminf(m1, fabsf(x));
        }
        minsum_store(v, off, m1, sflip, w, c2v);
    }
}

// ---- VN phase: exactly one 17x64 tile per block (24 tiles per group) ----
__device__ __forceinline__ void vn_pass(
    const float* __restrict__ xa, const signed char* __restrict__ c2v,
    float* __restrict__ tot, float* __restrict__ out_it,
    const int* __restrict__ sdeg, const int* __restrict__ svoff,
    int write_tot, float (*tile)[65], int g, int r)
{
    const int wave = threadIdx.x >> 6;
    const int lane = threadIdx.x & 63;
    const int zq = r >> 2, nc = r & 3;   // 24 = 6 z-quads x 4 n-chunks
    const int z0 = zq * 64, n0 = nc * 17;
    const int z  = z0 + lane;
    const int bz = g * Zz + z;           // offset within a c2v edge-row

    for (int i = wave; i < 17; i += 4) {
        int n = __builtin_amdgcn_readfirstlane(n0 + i);
        int d = __builtin_amdgcn_readfirstlane(sdeg[n]);     // wave-uniform
        const int* vo = svoff + n * PADD;                    // LDS broadcast
        int acc = 0;                 // sum of int8 messages (2x value): exact
        #pragma unroll
        for (int j = 0; j < 8; j++) acc += (int)c2v[vo[j] + bz];
        if (d > 8) {
            #pragma unroll
            for (int j = 8; j < 16; j++) acc += (int)c2v[vo[j] + bz];
        }
        if (d > 16) {
            #pragma unroll
            for (int j = 16; j < PADD; j++) acc += (int)c2v[vo[j] + bz];
        }
        float s = xa[(size_t)(g * Nn + n) * Zz + z] + 0.5f * (float)acc;
        if (write_tot) tot[(n * Bb + g) * Zz + z] = s;
        tile[i][lane] = s;
    }
    __syncthreads();

    // out[it][b][z][n]: 64 z-rows x 17 contiguous floats (68 B segments)
    float* dst = out_it + ((size_t)g * Zz + z0) * Nn + n0;
    for (int idx = threadIdx.x; idx < 17 * 64; idx += BLK) {
        int zz = idx / 17;
        int nn = idx - zz * 17;
        dst[(size_t)zz * Nn + nn] = tile[nn][zz];
    }
    __syncthreads();                     // tile protected before any reuse
}

__global__ __launch_bounds__(BLK, 6) void fused_kernel(
    const float* __restrict__ xa, const float* __restrict__ cn_weight,
    const int* __restrict__ edge_vn, const int* __restrict__ edge_shift,
    float* __restrict__ tot, signed char* __restrict__ c2v,
    unsigned* __restrict__ bar, float* __restrict__ out)
{
    __shared__ float tile[17][65];       // [n_local][z_local+1 pad]
    __shared__ int   svoff[Nn * PADD];   // per-VN byte offsets (dummy-padded)
    __shared__ int   sdeg[Nn];

    const int r = blockIdx.x;            // rank within group [0, 24)
    const int g = blockIdx.y;            // group = batch b   [0, 64)

    // ---- per-block LDS gather tables (order-independent -> bit-exact) ----
    for (int i = threadIdx.x; i < Nn; i += BLK) sdeg[i] = 0;
    for (int i = threadIdx.x; i < Nn * PADD; i += BLK) svoff[i] = Ee * ROWB;
    __syncthreads();
    for (int e = threadIdx.x; e < Ee; e += BLK) {
        int n = edge_vn[e];
        int slot = atomicAdd(&sdeg[n], 1);
        if (slot < PADD) svoff[n * PADD + slot] = e * ROWB;
    }
    // ---- zero this group's 384 B dummy-row slice (read via svoff padding) ----
    if (r == 0) {
        int* p = (int*)(c2v + (size_t)Ee * ROWB + g * Zz);
        for (int i = threadIdx.x; i < Zz / 4; i += BLK) p[i] = 0;
    }
    __syncthreads();                     // tables ready (dummy ordered by bar 0)

    unsigned* gb = bar + g * 16;         // this group's 64 B counter line

    for (int it = 0; it < ITERS; ++it) {
        const float w = cn_weight[it];
        if (it == 0) cn_pass<true >(xa,  c2v, edge_vn, edge_shift, w, g, r);
        else         cn_pass<false>(tot, c2v, edge_vn, edge_shift, w, g, r);
        gbar(gb + 2 * it);                           // group's c2v slice ready
        vn_pass(xa, c2v, tot, out + (size_t)it * OUT_ITER,
                sdeg, svoff, (it != ITERS - 1) ? 1 : 0, tile, g, r);
        if (it != ITERS - 1) gbar(gb + 2 * it + 1);  // group's tot slice ready
    }
}

extern "C" void kernel_launch(void* const* d_in, const int* in_sizes, int n_in,
                              void* d_out, int out_size, void* d_ws, size_t ws_size,
                              hipStream_t stream) {
    const float* xa        = (const float*)d_in[0];  // [B][N][Z]
    const float* cn_weight = (const float*)d_in[1];  // [ITERS]
    const int*   edge_vn   = (const int*)d_in[2];    // [E]
    // d_in[3] = edge_cn: structurally e % M, not needed
    const int*   edge_shift= (const int*)d_in[4];    // [E]
    float* out = (float*)d_out;                      // [ITERS][B][Z][N]

    char* ws = (char*)d_ws;
    float*       tot = (float*)(ws + TOT_OFF);
    signed char* c2v = (signed char*)(ws + C2V_OFF);
    unsigned*    bar = (unsigned*)(ws + BAR_OFF);

    // zero the 64 x 64 B barrier lines — capture-safe, re-poison-proof
    hipMemsetAsync(ws + BAR_OFF, 0, GROUPS * 64, stream);

    fused_kernel<<<dim3(GBLK, GROUPS), dim3(BLK), 0, stream>>>(
        xa, cn_weight, edge_vn, edge_shift, tot, c2v, bar, out);
}

// Round 5
// 223.551 us; speedup vs baseline: 8.5677x; 3.4315x over previous
//
#include <hip/hip_runtime.h>

// BoostedNeuralLDPCDecoder — MI355X HIP implementation (round 9)
//
// Round 8 post-mortem: barrier polls were fine; the cost was CACHE
// MAINTENANCE. Every block's release fetch_add ran buffer_wbl2 (full dirty-L2
// writeback) and every exit fence ran buffer_inv (full L2 invalidate):
// 9 barriers x 1536 blocks of whole-L2 ops serialized at each XCD's TCC,
// plus 157 MB of refetch for the evicted read-only working set.
//
// Round 9: ZERO fences. All cross-block-mutable data (c2v, tot, dummy row)
// uses LLC-direct accesses (sc0 sc1 = bypass L1 and the non-coherent L2;
// served by the always-coherent memory-side Infinity Cache):
//  * barrier: relaxed system-scope fetch_add + relaxed system-scope polls;
//    valve = fetch_add(+0) every 32 polls (RMW always executes at the
//    coherence point -> can never be stale-served -> no hang, no inv).
//  * mutable loads issued in asm batches (8-24 in flight), one
//    s_waitcnt vmcnt(0) + sched_barrier(0) per batch (rule #18).
//  * read-only xa/edge tables stay normally cached and are NEVER invalidated.
//  * __syncthreads() before the arrival add drains all waves' stores (vmcnt),
//    so data reaches LLC before the counter increment is observable.
// Arithmetic identical to round 4 (absmax 0.0 must be preserved).
//
// Layouts (lane = z => coalesced, incl. shifted circulant access):
//   tot  [N][B][Z] float      (6.68 MB)   — LLC-direct
//   c2v  [E+1][B][Z] int8     (9.07 MB)   — LLC-direct; row E = zero dummy
//   bar  [64 groups][16 uints] (4 KB; one 64 B line per group, 9 used)

#define ITERS 5
#define Nn 68
#define Mm 46
#define Zz 384
#define Ee 368
#define Bb 64
#define Kk 8          // edges per CN (E/M)
#define PADD 24       // padded max VN degree
#define BIGF 1e9f

#define ROWB (Bb*Zz)                     // 24,576 bytes per c2v edge-row
#define TOT_ELEMS (Nn*Bb*Zz)             // 1,671,168 floats
#define C2V_BYTES ((Ee+1)*ROWB)          // 9,068,544 bytes (incl. zero row)
#define TOT_OFF   0
#define C2V_OFF   (TOT_ELEMS*4)          // 6,684,672
#define BAR_OFF   (C2V_OFF + C2V_BYTES)  // 15,753,216; 4 KB of counters
// total ws need: BAR_OFF + 4096 = 15,757,312 bytes

#define BLK 256
#define GBLK 24                          // blocks per group (= per batch b)
#define GROUPS 64                        // one group per b; 24*64 = 1536 blocks
#define CNU (Mm*Zz)                      // 17,664 check-lane units per group
#define OUT_ITER ((size_t)Bb*Zz*Nn)

// ---- asm helpers: LLC-direct (sc0 sc1) access, batched-load discipline ----
__device__ __forceinline__ void wait_vm0() {
    asm volatile("s_waitcnt vmcnt(0)" ::: "memory");
    __builtin_amdgcn_sched_barrier(0);   // rule #18: pin uses below the wait
}
__device__ __forceinline__ void store_b8_llc(signed char* p, int q) {
    asm volatile("global_store_byte %0, %1, off sc0 sc1"
                 :: "v"(p), "v"(q) : "memory");
}
__device__ __forceinline__ void store_f32_llc(float* p, float s) {
    asm volatile("global_store_dword %0, %1, off sc0 sc1"
                 :: "v"(p), "v"(s) : "memory");
}

// ---- per-group barrier: fence-free ----
__device__ __forceinline__ void gbar(unsigned* __restrict__ ctr)
{
    __syncthreads();                     // all waves' LLC stores vmcnt-drained
    if (threadIdx.x == 0) {
        __hip_atomic_fetch_add(ctr, 1u, __ATOMIC_RELAXED,
                               __HIP_MEMORY_SCOPE_SYSTEM);
        int spins = 0;
        for (;;) {
            unsigned c = __hip_atomic_load(ctr, __ATOMIC_RELAXED,
                                           __HIP_MEMORY_SCOPE_SYSTEM);
            if (c >= (unsigned)GBLK) break;
            __builtin_amdgcn_s_sleep(4);
            if ((++spins & 31) == 0) {   // RMW valve: coherent by construction
                c = __hip_atomic_fetch_add(ctr, 0u, __ATOMIC_RELAXED,
                                           __HIP_MEMORY_SCOPE_SYSTEM);
                if (c >= (unsigned)GBLK) break;
            }
        }
    }
    __syncthreads();
}

// ---- min-sum tail: round-4 arithmetic, LLC-direct stores ----
__device__ __forceinline__ void minsum_store(
    const float v[Kk], const int off[Kk], float m1, unsigned sflip,
    float w, signed char* __restrict__ c2v)
{
    // min2 over entries whose |v| != min1 (reference tie semantics, BIG if none)
    float m2 = BIGF;
    #pragma unroll
    for (int k = 0; k < Kk; k++) {
        float mag = fabsf(v[k]);
        if (mag != m1) m2 = fminf(m2, mag);
    }
    #pragma unroll
    for (int k = 0; k < Kk; k++) {
        float mag  = fabsf(v[k]);
        float emin = (mag == m1) ? m2 : m1;
        unsigned neg = sflip ^ ((v[k] < 0.0f) ? 1u : 0u);  // csign * own_sign
        float ext = neg ? -emin : emin;
        // _qms5(w * ext): forward == clip(rintf(2*x)/2, +-7.5); store 2*q as int8
        float r = rintf(w * ext * 2.0f);
        r = fminf(15.0f, fmaxf(-15.0f, r));
        store_b8_llc(c2v + off[k], (int)r);
    }
}

// ---- CN phase for one group (batch b = g); FIRST reads xa (c2v == 0) ----
template<bool FIRST>
__device__ __forceinline__ void cn_pass(
    const float* __restrict__ src,       // FIRST ? xa [B][N][Z] : tot [N][B][Z]
    signed char* __restrict__ c2v,
    const int* __restrict__ edge_vn, const int* __restrict__ edge_shift,
    float w, int g, int r)
{
    for (int u = r * BLK + threadIdx.x; u < CNU; u += GBLK * BLK) {
        // whole wave lies in one cn: base 64-aligned and 64 | 384
        const int cn = __builtin_amdgcn_readfirstlane(u) / Zz;
        const int zc = u - cn * Zz;      // per-lane lifted row

        float v[Kk];
        int   off[Kk];
        float tv[Kk];
        int   cv[Kk];

        #pragma unroll
        for (int k = 0; k < Kk; k++) {   // issue all 16 loads, no wait yet
            int e  = cn + k * Mm;        // edges of this check (edge_cn = e % M)
            int sh = edge_shift[e];      // wave-uniform -> scalar load
            int n  = edge_vn[e];         // wave-uniform
            int z  = zc - sh;
            z += (z >> 31) & Zz;         // mod Z
            int o = e * ROWB + g * Zz + z;
            off[k] = o;
            if (FIRST) {
                tv[k] = src[(g * Nn + n) * Zz + z];   // cached xa load
            } else {
                const float* tp = src + (n * Bb + g) * Zz + z;
                asm volatile("global_load_dword %0, %1, off sc0 sc1"
                             : "=v"(tv[k]) : "v"(tp));
                const signed char* cp = c2v + o;
                asm volatile("global_load_sbyte %0, %1, off sc0 sc1"
                             : "=v"(cv[k]) : "v"(cp));
            }
        }
        if (!FIRST) wait_vm0();

        float m1 = BIGF;
        unsigned sflip = 0u;
        #pragma unroll
        for (int k = 0; k < Kk; k++) {
            float x = FIRST ? tv[k]
                            : (tv[k] - 0.5f * (float)cv[k]); // one rounding
            x = fminf(20.0f, fmaxf(-20.0f, x));  // allowed_llr_range
            v[k] = x;
            if (x < 0.0f) sflip ^= 1u;
            m1 = fminf(m1, fabsf(x));
        }
        minsum_store(v, off, m1, sflip, w, c2v);
    }
}

// ---- VN phase: exactly one 17x64 tile per block (24 tiles per group) ----
__device__ __forceinline__ void vn_pass(
    const float* __restrict__ xa, const signed char* __restrict__ c2v,
    float* __restrict__ tot, float* __restrict__ out_it,
    const int* __restrict__ sdeg, const int* __restrict__ svoff,
    int write_tot, float (*tile)[65], int g, int r)
{
    const int wave = threadIdx.x >> 6;
    const int lane = threadIdx.x & 63;
    const int zq = r >> 2, nc = r & 3;   // 24 = 6 z-quads x 4 n-chunks
    const int z0 = zq * 64, n0 = nc * 17;
    const int z  = z0 + lane;
    const int bz = g * Zz + z;           // offset within a c2v edge-row

    for (int i = wave; i < 17; i += 4) {
        int n = __builtin_amdgcn_readfirstlane(n0 + i);
        int d = __builtin_amdgcn_readfirstlane(sdeg[n]);     // wave-uniform
        const int* vo = svoff + n * PADD;                    // LDS broadcast
        int q0[8], q1[8], q2[8];
        #pragma unroll
        for (int j = 0; j < 8; j++) {    // batch 0: always issued
            const signed char* p = c2v + (vo[j] + bz);
            asm volatile("global_load_sbyte %0, %1, off sc0 sc1"
                         : "=v"(q0[j]) : "v"(p));
        }
        if (d > 8) {
            #pragma unroll
            for (int j = 0; j < 8; j++) {
                const signed char* p = c2v + (vo[8 + j] + bz);
                asm volatile("global_load_sbyte %0, %1, off sc0 sc1"
                             : "=v"(q1[j]) : "v"(p));
            }
        }
        if (d > 16) {
            #pragma unroll
            for (int j = 0; j < 8; j++) {
                const signed char* p = c2v + (vo[16 + j] + bz);
                asm volatile("global_load_sbyte %0, %1, off sc0 sc1"
                             : "=v"(q2[j]) : "v"(p));
            }
        }
        wait_vm0();                      // all <=24 loads land together

        int acc = 0;                     // sum of int8 messages (2x): exact
        #pragma unroll
        for (int j = 0; j < 8; j++) acc += q0[j];
        if (d > 8) {
            #pragma unroll
            for (int j = 0; j < 8; j++) acc += q1[j];
        }
        if (d > 16) {
            #pragma unroll
            for (int j = 0; j < 8; j++) acc += q2[j];
        }
        float s = xa[(size_t)(g * Nn + n) * Zz + z] + 0.5f * (float)acc;
        if (write_tot) store_f32_llc(tot + (n * Bb + g) * Zz + z, s);
        tile[i][lane] = s;
    }
    __syncthreads();

    // out[it][b][z][n]: 64 z-rows x 17 contiguous floats (68 B segments);
    // normal cached stores (no in-kernel reader; kernel-end flush publishes)
    float* dst = out_it + ((size_t)g * Zz + z0) * Nn + n0;
    for (int idx = threadIdx.x; idx < 17 * 64; idx += BLK) {
        int zz = idx / 17;
        int nn = idx - zz * 17;
        dst[(size_t)zz * Nn + nn] = tile[nn][zz];
    }
    __syncthreads();                     // tile protected before any reuse
}

__global__ __launch_bounds__(BLK, 6) void fused_kernel(
    const float* __restrict__ xa, const float* __restrict__ cn_weight,
    const int* __restrict__ edge_vn, const int* __restrict__ edge_shift,
    float* __restrict__ tot, signed char* __restrict__ c2v,
    unsigned* __restrict__ bar, float* __restrict__ out)
{
    __shared__ float tile[17][65];       // [n_local][z_local+1 pad]
    __shared__ int   svoff[Nn * PADD];   // per-VN byte offsets (dummy-padded)
    __shared__ int   sdeg[Nn];

    const int r = blockIdx.x;            // rank within group [0, 24)
    const int g = blockIdx.y;            // group = batch b   [0, 64)

    // ---- per-block LDS gather tables (order-independent -> bit-exact) ----
    for (int i = threadIdx.x; i < Nn; i += BLK) sdeg[i] = 0;
    for (int i = threadIdx.x; i < Nn * PADD; i += BLK) svoff[i] = Ee * ROWB;
    __syncthreads();
    for (int e = threadIdx.x; e < Ee; e += BLK) {
        int n = edge_vn[e];
        int slot = atomicAdd(&sdeg[n], 1);
        if (slot < PADD) svoff[n * PADD + slot] = e * ROWB;
    }
    // ---- zero this group's 384 B dummy-row slice — LLC-direct so padded
    //      gather slots (read LLC-direct after barrier 0) see zeros ----
    if (r == 0) {
        int* p = (int*)(c2v + (size_t)Ee * ROWB + g * Zz);
        int zero = 0;
        for (int i = threadIdx.x; i < Zz / 4; i += BLK)
            asm volatile("global_store_dword %0, %1, off sc0 sc1"
                         :: "v"(p + i), "v"(zero) : "memory");
    }
    __syncthreads();                     // tables ready; zeros drain by bar 0

    unsigned* gb = bar + g * 16;         // this group's 64 B counter line

    for (int it = 0; it < ITERS; ++it) {
        const float w = cn_weight[it];
        if (it == 0) cn_pass<true >(xa,  c2v, edge_vn, edge_shift, w, g, r);
        else         cn_pass<false>(tot, c2v, edge_vn, edge_shift, w, g, r);
        gbar(gb + 2 * it);                           // group's c2v slice ready
        vn_pass(xa, c2v, tot, out + (size_t)it * OUT_ITER,
                sdeg, svoff, (it != ITERS - 1) ? 1 : 0, tile, g, r);
        if (it != ITERS - 1) gbar(gb + 2 * it + 1);  // group's tot slice ready
    }
}

extern "C" void kernel_launch(void* const* d_in, const int* in_sizes, int n_in,
                              void* d_out, int out_size, void* d_ws, size_t ws_size,
                              hipStream_t stream) {
    const float* xa        = (const float*)d_in[0];  // [B][N][Z]
    const float* cn_weight = (const float*)d_in[1];  // [ITERS]
    const int*   edge_vn   = (const int*)d_in[2];    // [E]
    // d_in[3] = edge_cn: structurally e % M, not needed
    const int*   edge_shift= (const int*)d_in[4];    // [E]
    float* out = (float*)d_out;                      // [ITERS][B][Z][N]

    char* ws = (char*)d_ws;
    float*       tot = (float*)(ws + TOT_OFF);
    signed char* c2v = (signed char*)(ws + C2V_OFF);
    unsigned*    bar = (unsigned*)(ws + BAR_OFF);

    // zero the 64 x 64 B barrier lines — capture-safe, re-poison-proof
    hipMemsetAsync(ws + BAR_OFF, 0, GROUPS * 64, stream);

    fused_kernel<<<dim3(GBLK, GROUPS), dim3(BLK), 0, stream>>>(
        xa, cn_weight, edge_vn, edge_shift, tot, c2v, bar, out);
}